// Round 1
// baseline (689.075 us; speedup 1.0000x reference)
//
#include <hip/hip_runtime.h>

#define B_ 2
#define T_ 2048
#define NH 16
#define NKV 8
#define HD 128
#define C_ 2048
#define KVD (NKV*HD)       // 1024
#define QKVD (C_ + 2*KVD)  // 4096
#define NTOK (B_*T_)       // 4096

typedef __bf16 bf16_t;
typedef __bf16 bf16x4_t __attribute__((ext_vector_type(4)));
typedef __bf16 bf16x8_t __attribute__((ext_vector_type(8)));
typedef float f32x4_t __attribute__((ext_vector_type(4)));

__device__ __forceinline__ f32x4_t mfma16(bf16x8_t a, bf16x8_t b, f32x4_t c) {
  return __builtin_amdgcn_mfma_f32_16x16x32_bf16(a, b, c, 0, 0, 0);
}

// ---------------- fp32 -> bf16 convert ----------------
__global__ __launch_bounds__(256) void cvt_kernel(const float* __restrict__ src,
                                                  bf16_t* __restrict__ dst, int n) {
  int i = (blockIdx.x * 256 + threadIdx.x) * 4;
  if (i >= n) return;
  const float4 v = *(const float4*)(src + i);
  bf16x4_t o;
  o[0] = (bf16_t)v.x; o[1] = (bf16_t)v.y; o[2] = (bf16_t)v.z; o[3] = (bf16_t)v.w;
  *(bf16x4_t*)(dst + i) = o;
}

// ---------------- bf16 NT GEMM: C[m][n] = sum_k A[m][k]*B[n][k], C fp32 ----------------
// 128x128 block tile, BK=32, 4 waves (2x2), each wave 64x64 via 4x4 MFMA 16x16x32.
__global__ __launch_bounds__(256) void gemm_nt(const bf16_t* __restrict__ A,
                                               const bf16_t* __restrict__ Bm,
                                               float* __restrict__ C, int M, int N, int K) {
  __shared__ bf16_t As[128*40];  // pad 32->40 elems (80B rows, 16B aligned)
  __shared__ bf16_t Bs[128*40];
  int tid = threadIdx.x;
  int wave = tid >> 6, lane = tid & 63;
  int quad = lane >> 4, l16 = lane & 15;
  int wm = (wave >> 1) * 64, wn = (wave & 1) * 64;
  int bm = blockIdx.y * 128, bn = blockIdx.x * 128;
  int srow = tid >> 2, scol = (tid & 3) * 8;
  f32x4_t acc[4][4];
  #pragma unroll
  for (int i = 0; i < 4; i++)
    #pragma unroll
    for (int j = 0; j < 4; j++) acc[i][j] = (f32x4_t){0.f,0.f,0.f,0.f};
  const bf16_t* pa = A + (size_t)(bm + srow) * K + scol;
  const bf16_t* pb = Bm + (size_t)(bn + srow) * K + scol;
  for (int k0 = 0; k0 < K; k0 += 32) {
    bf16x8_t a0 = *(const bf16x8_t*)(pa + k0);
    bf16x8_t a1 = *(const bf16x8_t*)(pa + (size_t)64*K + k0);
    bf16x8_t b0 = *(const bf16x8_t*)(pb + k0);
    bf16x8_t b1 = *(const bf16x8_t*)(pb + (size_t)64*K + k0);
    __syncthreads();  // previous iteration's frag reads complete
    *(bf16x8_t*)&As[srow*40 + scol] = a0;
    *(bf16x8_t*)&As[(srow+64)*40 + scol] = a1;
    *(bf16x8_t*)&Bs[srow*40 + scol] = b0;
    *(bf16x8_t*)&Bs[(srow+64)*40 + scol] = b1;
    __syncthreads();
    bf16x8_t af[4], bfr[4];
    #pragma unroll
    for (int i = 0; i < 4; i++) {
      af[i]  = *(const bf16x8_t*)&As[(wm + i*16 + l16)*40 + quad*8];
      bfr[i] = *(const bf16x8_t*)&Bs[(wn + i*16 + l16)*40 + quad*8];
    }
    #pragma unroll
    for (int i = 0; i < 4; i++)
      #pragma unroll
      for (int j = 0; j < 4; j++)
        acc[i][j] = mfma16(af[i], bfr[j], acc[i][j]);
  }
  // C/D layout: col = lane&15, row = quad*4 + reg
  #pragma unroll
  for (int i = 0; i < 4; i++)
    #pragma unroll
    for (int j = 0; j < 4; j++) {
      int row0 = bm + wm + i*16 + quad*4;
      int col  = bn + wn + j*16 + l16;
      #pragma unroll
      for (int r = 0; r < 4; r++)
        C[(size_t)(row0 + r) * N + col] = acc[i][j][r];
    }
}

// ---------------- RoPE + RMSNorm + layout change, qkv fp32 -> q/k/v bf16 ----------------
// One wave per (token, slot). slots 0..15 = q heads, 16..23 = k heads, 24..31 = v heads.
// Lane i owns rotary pair (i, i+64). q pre-scaled by (1/sqrt(128))*log2(e) for exp2 softmax.
__global__ __launch_bounds__(256) void rope_norm_kernel(const float* __restrict__ qkv,
    const float* __restrict__ cosb, const float* __restrict__ sinb,
    bf16_t* __restrict__ qb, bf16_t* __restrict__ kb, bf16_t* __restrict__ vb) {
  int task = blockIdx.x * 4 + (threadIdx.x >> 6);
  int lane = threadIdx.x & 63;
  int token = task >> 5;
  int slot = task & 31;
  int b = token >> 11, s = token & 2047;
  const float* row = qkv + (size_t)token * QKVD;
  if (slot < 24) {
    int base_in = (slot < 16) ? slot * HD : C_ + (slot - 16) * HD;
    float x1 = row[base_in + lane];
    float x2 = row[base_in + 64 + lane];
    float c = cosb[s*64 + lane], sn = sinb[s*64 + lane];
    float y1 = x1*c + x2*sn;
    float y2 = x2*c - x1*sn;
    float ss = y1*y1 + y2*y2;
    ss += __shfl_xor(ss, 1);  ss += __shfl_xor(ss, 2);  ss += __shfl_xor(ss, 4);
    ss += __shfl_xor(ss, 8);  ss += __shfl_xor(ss, 16); ss += __shfl_xor(ss, 32);
    float r = rsqrtf(ss * (1.0f/128.0f) + 1.1920929e-07f);
    bf16_t* dst;
    if (slot < 16) {
      r *= 0.08838834764831845f * 1.4426950408889634f;  // 1/sqrt(128) * log2(e)
      dst = qb + ((size_t)(b*NH + slot) * T_ + s) * HD;
    } else {
      dst = kb + ((size_t)(b*NKV + (slot-16)) * T_ + s) * HD;
    }
    dst[lane]      = (bf16_t)(y1 * r);
    dst[lane + 64] = (bf16_t)(y2 * r);
  } else {
    int kv = slot - 24;
    int base_in = C_ + KVD + kv * HD;
    bf16_t* dst = vb + ((size_t)(b*NKV + kv) * T_ + s) * HD;
    dst[lane]      = (bf16_t)row[base_in + lane];
    dst[lane + 64] = (bf16_t)row[base_in + 64 + lane];
  }
}

// ---------------- flash attention (causal, GQA rep=2), bf16 in/out, fp32 online softmax ----------------
// Block: 4 waves, 128 Q rows (32 per wave), 64-key tiles. exp2 domain (scale folded into q).
__global__ __launch_bounds__(256) void attn_kernel(const bf16_t* __restrict__ qb,
    const bf16_t* __restrict__ kb, const bf16_t* __restrict__ vb, bf16_t* __restrict__ yb) {
  __shared__ bf16_t Ks[64*136];    // (key, d) pad 128->136
  __shared__ bf16_t Vs[128*72];    // transposed (d, key) pad 64->72
  __shared__ bf16_t Ps[4][32*72];  // per-wave P, (qrow, key) pad 64->72
  int bh = blockIdx.y;
  int b = bh >> 4, h = bh & 15;
  int kvh = h >> 1;
  int q0 = blockIdx.x * 128;
  int tid = threadIdx.x, wave = tid >> 6, lane = tid & 63, quad = lane >> 4, l16 = lane & 15;
  int wrow = wave * 32;
  const bf16_t* Qp = qb + (size_t)bh * T_ * HD;
  const bf16_t* Kp = kb + (size_t)(b*NKV + kvh) * T_ * HD;
  const bf16_t* Vp = vb + (size_t)(b*NKV + kvh) * T_ * HD;

  bf16x8_t qf[2][4];
  #pragma unroll
  for (int i = 0; i < 2; i++)
    #pragma unroll
    for (int kk = 0; kk < 4; kk++)
      qf[i][kk] = *(const bf16x8_t*)(Qp + (size_t)(q0 + wrow + i*16 + l16)*HD + kk*32 + quad*8);

  float m[2][4], l[2][4];
  f32x4_t o[2][8];
  #pragma unroll
  for (int i = 0; i < 2; i++)
    #pragma unroll
    for (int r = 0; r < 4; r++) { m[i][r] = -1e30f; l[i][r] = 0.f; }
  #pragma unroll
  for (int i = 0; i < 2; i++)
    #pragma unroll
    for (int nb = 0; nb < 8; nb++) o[i][nb] = (f32x4_t){0.f,0.f,0.f,0.f};

  int srow16 = tid >> 4, scol8 = (tid & 15) * 8;
  int ntiles = q0/64 + 2;
  for (int t = 0; t < ntiles; t++) {
    int k0 = t * 64;
    __syncthreads();  // previous iteration's Ks/Vs reads complete
    #pragma unroll
    for (int p = 0; p < 4; p++) {
      int r = p*16 + srow16;
      *(bf16x8_t*)&Ks[r*136 + scol8] = *(const bf16x8_t*)(Kp + (size_t)(k0 + r)*HD + scol8);
    }
    #pragma unroll
    for (int p = 0; p < 4; p++) {
      int r = p*16 + srow16;
      bf16x8_t vv = *(const bf16x8_t*)(Vp + (size_t)(k0 + r)*HD + scol8);
      #pragma unroll
      for (int e = 0; e < 8; e++) Vs[(scol8 + e)*72 + r] = vv[e];
    }
    __syncthreads();

    // S = Q K^T  (this wave's 32 rows x 64 keys)
    f32x4_t sacc[2][4];
    #pragma unroll
    for (int i = 0; i < 2; i++)
      #pragma unroll
      for (int nb = 0; nb < 4; nb++) sacc[i][nb] = (f32x4_t){0.f,0.f,0.f,0.f};
    #pragma unroll
    for (int nb = 0; nb < 4; nb++) {
      bf16x8_t kf[4];
      #pragma unroll
      for (int kk = 0; kk < 4; kk++)
        kf[kk] = *(const bf16x8_t*)&Ks[(nb*16 + l16)*136 + kk*32 + quad*8];
      #pragma unroll
      for (int i = 0; i < 2; i++)
        #pragma unroll
        for (int kk = 0; kk < 4; kk++)
          sacc[i][nb] = mfma16(qf[i][kk], kf[kk], sacc[i][nb]);
    }
    // causal mask
    if (k0 + 63 > q0 + wrow) {
      #pragma unroll
      for (int i = 0; i < 2; i++)
        #pragma unroll
        for (int nb = 0; nb < 4; nb++)
          #pragma unroll
          for (int r = 0; r < 4; r++) {
            int qr = q0 + wrow + i*16 + quad*4 + r;
            int kc = k0 + nb*16 + l16;
            if (kc > qr) sacc[i][nb][r] = -1e30f;
          }
    }
    // online softmax (rows live in 16-lane groups; reduce over lane&15)
    #pragma unroll
    for (int i = 0; i < 2; i++) {
      #pragma unroll
      for (int r = 0; r < 4; r++) {
        float v = fmaxf(fmaxf(sacc[i][0][r], sacc[i][1][r]), fmaxf(sacc[i][2][r], sacc[i][3][r]));
        v = fmaxf(v, __shfl_xor(v, 1));
        v = fmaxf(v, __shfl_xor(v, 2));
        v = fmaxf(v, __shfl_xor(v, 4));
        v = fmaxf(v, __shfl_xor(v, 8));
        float mn = fmaxf(m[i][r], v);
        float alpha = exp2f(m[i][r] - mn);
        m[i][r] = mn;
        float rsum = 0.f;
        #pragma unroll
        for (int nb = 0; nb < 4; nb++) {
          float p = exp2f(sacc[i][nb][r] - mn);
          sacc[i][nb][r] = p;
          rsum += p;
        }
        rsum += __shfl_xor(rsum, 1);
        rsum += __shfl_xor(rsum, 2);
        rsum += __shfl_xor(rsum, 4);
        rsum += __shfl_xor(rsum, 8);
        l[i][r] = l[i][r] * alpha + rsum;
        #pragma unroll
        for (int nb = 0; nb < 8; nb++) o[i][nb][r] *= alpha;
        int prow = i*16 + quad*4 + r;
        #pragma unroll
        for (int nb = 0; nb < 4; nb++)
          Ps[wave][prow*72 + nb*16 + l16] = (bf16_t)sacc[i][nb][r];
      }
    }
    // O += P V   (P via LDS for C-layout -> A-layout; wave-local, no barrier needed)
    bf16x8_t pf[2][2];
    #pragma unroll
    for (int i = 0; i < 2; i++)
      #pragma unroll
      for (int kk = 0; kk < 2; kk++)
        pf[i][kk] = *(const bf16x8_t*)&Ps[wave][(i*16 + l16)*72 + kk*32 + quad*8];
    #pragma unroll
    for (int nb = 0; nb < 8; nb++) {
      bf16x8_t vf[2];
      #pragma unroll
      for (int kk = 0; kk < 2; kk++)
        vf[kk] = *(const bf16x8_t*)&Vs[(nb*16 + l16)*72 + kk*32 + quad*8];
      #pragma unroll
      for (int i = 0; i < 2; i++)
        #pragma unroll
        for (int kk = 0; kk < 2; kk++)
          o[i][nb] = mfma16(pf[i][kk], vf[kk], o[i][nb]);
    }
  }
  // epilogue: O/l -> yb in (B,T,NH*HD) layout for proj GEMM
  #pragma unroll
  for (int i = 0; i < 2; i++)
    #pragma unroll
    for (int r = 0; r < 4; r++) {
      float invl = 1.0f / l[i][r];
      int row = q0 + wrow + i*16 + quad*4 + r;
      size_t base = ((size_t)(b*T_ + row) * NH + h) * HD;
      #pragma unroll
      for (int nb = 0; nb < 8; nb++)
        yb[base + nb*16 + l16] = (bf16_t)(o[i][nb][r] * invl);
    }
}

extern "C" void kernel_launch(void* const* d_in, const int* in_sizes, int n_in,
                              void* d_out, int out_size, void* d_ws, size_t ws_size,
                              hipStream_t stream) {
  const float* x      = (const float*)d_in[0];
  const float* w_attn = (const float*)d_in[1];
  const float* w_proj = (const float*)d_in[2];
  const float* cosb   = (const float*)d_in[3];
  const float* sinb   = (const float*)d_in[4];
  float* out = (float*)d_out;

  // workspace layout (all 16B-aligned)
  bf16_t* xb  = (bf16_t*)d_ws;          // 8388608 bf16
  bf16_t* wab = xb + 8388608;           // 8388608 bf16
  bf16_t* wpb = wab + 8388608;          // 4194304 bf16
  float*  qkv = (float*)(wpb + 4194304);// 16777216 fp32
  bf16_t* qb  = (bf16_t*)(qkv + 16777216); // 8388608 bf16
  bf16_t* kb  = qb + 8388608;           // 4194304 bf16
  bf16_t* vb  = kb + 4194304;           // 4194304 bf16
  bf16_t* yb  = vb + 4194304;           // 8388608 bf16

  cvt_kernel<<<8192, 256, 0, stream>>>(x, xb, 8388608);
  cvt_kernel<<<8192, 256, 0, stream>>>(w_attn, wab, 8388608);
  cvt_kernel<<<4096, 256, 0, stream>>>(w_proj, wpb, 4194304);

  // qkv = x @ w_attn^T  : M=4096, N=4096, K=2048
  gemm_nt<<<dim3(32, 32), 256, 0, stream>>>(xb, wab, qkv, NTOK, QKVD, C_);

  rope_norm_kernel<<<32768, 256, 0, stream>>>(qkv, cosb, sinb, qb, kb, vb);

  attn_kernel<<<dim3(16, 32), 256, 0, stream>>>(qb, kb, vb, yb);

  // out = y @ w_proj^T : M=4096, N=2048, K=2048
  gemm_nt<<<dim3(16, 32), 256, 0, stream>>>(yb, wpb, out, NTOK, C_, C_);
}

// Round 2
// 359.599 us; speedup vs baseline: 1.9162x; 1.9162x over previous
//
#include <hip/hip_runtime.h>

#define B_ 2
#define T_ 2048
#define NH 16
#define NKV 8
#define HD 128
#define C_ 2048
#define KVD (NKV*HD)       // 1024
#define QKVD (C_ + 2*KVD)  // 4096
#define NTOK (B_*T_)       // 4096

typedef __bf16 bf16_t;
typedef __bf16 bf16x4_t __attribute__((ext_vector_type(4)));
typedef __bf16 bf16x8_t __attribute__((ext_vector_type(8)));
typedef float f32x4_t __attribute__((ext_vector_type(4)));

__device__ __forceinline__ f32x4_t mfma16(bf16x8_t a, bf16x8_t b, f32x4_t c) {
  return __builtin_amdgcn_mfma_f32_16x16x32_bf16(a, b, c, 0, 0, 0);
}

// async global->LDS, 16B per lane; LDS dest = wave-uniform base + lane*16
#define GLDS16(gp, lp) __builtin_amdgcn_global_load_lds( \
    (const __attribute__((address_space(1))) void*)(gp), \
    (__attribute__((address_space(3))) void*)(lp), 16, 0, 0)

// ---------------- fp32 -> bf16 convert ----------------
__global__ __launch_bounds__(256) void cvt_kernel(const float* __restrict__ src,
                                                  bf16_t* __restrict__ dst, int n) {
  int i = (blockIdx.x * 256 + threadIdx.x) * 4;
  if (i >= n) return;
  const float4 v = *(const float4*)(src + i);
  bf16x4_t o;
  o[0] = (bf16_t)v.x; o[1] = (bf16_t)v.y; o[2] = (bf16_t)v.z; o[3] = (bf16_t)v.w;
  *(bf16x4_t*)(dst + i) = o;
}

// ---------------- bf16 NT GEMM (m97 pattern): C[m][n] = sum_k A[m][k]*B[n][k] ----------------
// 128x128 tile, BK=32, global_load_lds width-16 staging, unpadded LDS (64B rows:
// frag-read bank base = 16*(l16&1)+4*quad -> uniform, conflict-free).
__global__ void gemm_nt(const bf16_t* __restrict__ A, const bf16_t* __restrict__ Bm,
                        float* __restrict__ C, int M, int N, int K) {
  __shared__ bf16_t As[128*32];
  __shared__ bf16_t Bs[128*32];
  int tid = threadIdx.x;
  int wave = tid >> 6, lane = tid & 63;
  int quad = lane >> 4, l16 = lane & 15;
  int wm = (wave >> 1) * 64, wn = (wave & 1) * 64;
  int bm = blockIdx.y * 128, bn = blockIdx.x * 128;
  int grow = wave * 32 + (lane >> 2);   // staging row (this wave stages rows [wave*32, wave*32+32))
  int gcol = (lane & 3) * 8;
  const bf16_t* pa = A + (size_t)(bm + grow) * K + gcol;
  const bf16_t* pb = Bm + (size_t)(bn + grow) * K + gcol;
  bf16_t* lA0 = &As[(wave * 32) * 32];
  bf16_t* lA1 = &As[(wave * 32 + 16) * 32];
  bf16_t* lB0 = &Bs[(wave * 32) * 32];
  bf16_t* lB1 = &Bs[(wave * 32 + 16) * 32];
  f32x4_t acc[4][4];
  #pragma unroll
  for (int i = 0; i < 4; i++)
    #pragma unroll
    for (int j = 0; j < 4; j++) acc[i][j] = (f32x4_t){0.f,0.f,0.f,0.f};
  for (int k0 = 0; k0 < K; k0 += 32) {
    __syncthreads();  // previous iteration's frag reads complete
    GLDS16(pa + k0, lA0);
    GLDS16(pa + (size_t)16 * K + k0, lA1);
    GLDS16(pb + k0, lB0);
    GLDS16(pb + (size_t)16 * K + k0, lB1);
    __syncthreads();  // drains vmcnt -> staged data visible
    bf16x8_t af[4], bfr[4];
    #pragma unroll
    for (int i = 0; i < 4; i++) {
      af[i]  = *(const bf16x8_t*)&As[(wm + i*16 + l16)*32 + quad*8];
      bfr[i] = *(const bf16x8_t*)&Bs[(wn + i*16 + l16)*32 + quad*8];
    }
    #pragma unroll
    for (int i = 0; i < 4; i++)
      #pragma unroll
      for (int j = 0; j < 4; j++)
        acc[i][j] = mfma16(af[i], bfr[j], acc[i][j]);
  }
  // C/D layout: col = lane&15, row = quad*4 + reg
  #pragma unroll
  for (int i = 0; i < 4; i++)
    #pragma unroll
    for (int j = 0; j < 4; j++) {
      int row0 = bm + wm + i*16 + quad*4;
      int col  = bn + wn + j*16 + l16;
      #pragma unroll
      for (int r = 0; r < 4; r++)
        C[(size_t)(row0 + r) * N + col] = acc[i][j][r];
    }
}

// ---------------- RoPE + RMSNorm, qkv fp32 -> q/k bf16 (v handled separately) ----------------
// One wave per (token, slot). slots 0..15 = q heads, 16..23 = k heads.
// Lane i owns rotary pair (i, i+64). q pre-scaled by (1/sqrt(128))*log2(e) for exp2 softmax.
__global__ __launch_bounds__(256) void rope_norm_kernel(const float* __restrict__ qkv,
    const float* __restrict__ cosb, const float* __restrict__ sinb,
    bf16_t* __restrict__ qb, bf16_t* __restrict__ kb) {
  int token = blockIdx.y;
  int slot = blockIdx.x * 4 + (threadIdx.x >> 6);
  int lane = threadIdx.x & 63;
  int b = token >> 11, s = token & 2047;
  const float* row = qkv + (size_t)token * QKVD;
  int base_in = (slot < 16) ? slot * HD : C_ + (slot - 16) * HD;
  float x1 = row[base_in + lane];
  float x2 = row[base_in + 64 + lane];
  float c = cosb[s*64 + lane], sn = sinb[s*64 + lane];
  float y1 = x1*c + x2*sn;
  float y2 = x2*c - x1*sn;
  float ss = y1*y1 + y2*y2;
  ss += __shfl_xor(ss, 1);  ss += __shfl_xor(ss, 2);  ss += __shfl_xor(ss, 4);
  ss += __shfl_xor(ss, 8);  ss += __shfl_xor(ss, 16); ss += __shfl_xor(ss, 32);
  float r = rsqrtf(ss * (1.0f/128.0f) + 1.1920929e-07f);
  bf16_t* dst;
  if (slot < 16) {
    r *= 0.08838834764831845f * 1.4426950408889634f;  // 1/sqrt(128) * log2(e)
    dst = qb + ((size_t)(b*NH + slot) * T_ + s) * HD;
  } else {
    dst = kb + ((size_t)(b*NKV + (slot-16)) * T_ + s) * HD;
  }
  dst[lane]      = (bf16_t)(y1 * r);
  dst[lane + 64] = (bf16_t)(y2 * r);
}

// ---------------- V: cast + transpose to (b, kvh, d, t) via LDS tile ----------------
__global__ __launch_bounds__(256) void transpose_v(const float* __restrict__ qkv,
                                                   bf16_t* __restrict__ vt) {
  __shared__ bf16_t TT[64*136];   // (tok, d) pad 128->136
  int bk = blockIdx.y;            // b*8 + kv
  int b = bk >> 3, kv = bk & 7;
  int s0 = blockIdx.x * 64;
  int tid = threadIdx.x;
  int row = tid >> 2, c0 = (tid & 3) * 32;
  const float* src = qkv + (size_t)(b*T_ + s0 + row) * QKVD + C_ + KVD + kv*HD + c0;
  #pragma unroll
  for (int s4 = 0; s4 < 8; s4++) {
    float4 v = *(const float4*)(src + s4*4);
    bf16x4_t pk;
    pk[0] = (bf16_t)v.x; pk[1] = (bf16_t)v.y; pk[2] = (bf16_t)v.z; pk[3] = (bf16_t)v.w;
    *(bf16x4_t*)&TT[row*136 + c0 + s4*4] = pk;
  }
  __syncthreads();
  #pragma unroll
  for (int s2 = 0; s2 < 2; s2++) {
    int d = (tid >> 2) + s2*64;
    #pragma unroll
    for (int s = 0; s < 2; s++) {
      int g = (tid & 3) * 8 + s*32;
      bf16x8_t pk;
      #pragma unroll
      for (int e = 0; e < 8; e++) pk[e] = TT[(g + e)*136 + d];
      *(bf16x8_t*)(vt + ((size_t)bk * HD + d) * T_ + s0 + g) = pk;
    }
  }
}

// ---------------- flash attention, S^T formulation ----------------
// S^T = K Q^T (A=K, B=Q): C-layout col=l16 = q-row -> each lane owns ONE q-row.
// Softmax: 16 local ops + 2 shuffles. O^T = V^T P (A=V^T from pre-transposed vt, B=P).
// 4 waves x 16 q-rows = 64-row phases; paired q-tiles (j, 31-j) -> 33 k-tiles/block, balanced.
__global__ __launch_bounds__(256, 2) void attn_kernel(const bf16_t* __restrict__ qb,
    const bf16_t* __restrict__ kb, const bf16_t* __restrict__ vt, bf16_t* __restrict__ yb) {
  __shared__ bf16_t Ks[64*136];    // (key, d) pad 128->136
  __shared__ bf16_t Vs[128*72];    // (d, key) pad 64->72  (from pre-transposed vt)
  __shared__ bf16_t Ps[4][16*72];  // per-wave P (qrow, key) pad 64->72
  int bh = blockIdx.y;
  int b = bh >> 4, h = bh & 15, kvh = h >> 1;
  int j = blockIdx.x;
  int tid = threadIdx.x, wave = tid >> 6, lane = tid & 63, quad = lane >> 4, l16 = lane & 15;
  const bf16_t* Qp = qb + (size_t)bh * T_ * HD;
  const bf16_t* Kp = kb + (size_t)(b*NKV + kvh) * T_ * HD;
  const bf16_t* Vt = vt + (size_t)(b*NKV + kvh) * HD * T_;

  int krow = tid >> 2, kc0 = (tid & 3) * 8;      // K staging map
  int vd = tid >> 1,  vc0 = (tid & 1) * 8;       // V staging map

  for (int ph = 0; ph < 2; ph++) {
    int qt = ph ? (31 - j) : j;
    int q0w = qt * 64 + wave * 16;
    bf16x8_t qf[4];
    #pragma unroll
    for (int kc = 0; kc < 4; kc++)
      qf[kc] = *(const bf16x8_t*)(Qp + (size_t)(q0w + l16) * HD + kc*32 + quad*8);

    float mrow = -1e30f, lrow = 0.f;
    f32x4_t o[8];
    #pragma unroll
    for (int mb = 0; mb < 8; mb++) o[mb] = (f32x4_t){0.f,0.f,0.f,0.f};

    int nkt = qt + 1;
    for (int kt = 0; kt < nkt; kt++) {
      int k0 = kt * 64;
      __syncthreads();  // previous tile's LDS reads (or prior-phase epilogue) complete
      {
        const bf16_t* src = Kp + (size_t)(k0 + krow) * HD + kc0;
        #pragma unroll
        for (int s = 0; s < 4; s++)
          *(bf16x8_t*)&Ks[krow*136 + kc0 + s*32] = *(const bf16x8_t*)(src + s*32);
      }
      {
        const bf16_t* src = Vt + (size_t)vd * T_ + k0 + vc0;
        #pragma unroll
        for (int s = 0; s < 4; s++)
          *(bf16x8_t*)&Vs[vd*72 + vc0 + s*16] = *(const bf16x8_t*)(src + s*16);
      }
      __syncthreads();

      // S^T = K Q^T : sacc[mb] holds key = k0+mb*16+quad*4+r, qrow = q0w+l16
      f32x4_t sacc[4];
      #pragma unroll
      for (int mb = 0; mb < 4; mb++) sacc[mb] = (f32x4_t){0.f,0.f,0.f,0.f};
      #pragma unroll
      for (int mb = 0; mb < 4; mb++)
        #pragma unroll
        for (int kc = 0; kc < 4; kc++) {
          bf16x8_t kf = *(const bf16x8_t*)&Ks[(mb*16 + l16)*136 + kc*32 + quad*8];
          sacc[mb] = mfma16(kf, qf[kc], sacc[mb]);
        }
      if (kt == qt) {  // diagonal tile: causal mask (local coords)
        int rowl = wave*16 + l16;
        #pragma unroll
        for (int mb = 0; mb < 4; mb++)
          #pragma unroll
          for (int r = 0; r < 4; r++)
            if (mb*16 + quad*4 + r > rowl) sacc[mb][r] = -1e30f;
      }
      // online softmax: each lane owns one q-row; reduce over quads (2 shuffles)
      float mx = -1e30f;
      #pragma unroll
      for (int mb = 0; mb < 4; mb++)
        #pragma unroll
        for (int r = 0; r < 4; r++) mx = fmaxf(mx, sacc[mb][r]);
      mx = fmaxf(mx, __shfl_xor(mx, 16));
      mx = fmaxf(mx, __shfl_xor(mx, 32));
      float mnew = fmaxf(mrow, mx);
      float alpha = exp2f(mrow - mnew);
      mrow = mnew;
      float rs = 0.f;
      #pragma unroll
      for (int mb = 0; mb < 4; mb++)
        #pragma unroll
        for (int r = 0; r < 4; r++) {
          float p = exp2f(sacc[mb][r] - mnew);
          sacc[mb][r] = p;
          rs += p;
        }
      rs += __shfl_xor(rs, 16);
      rs += __shfl_xor(rs, 32);
      lrow = lrow * alpha + rs;
      #pragma unroll
      for (int mb = 0; mb < 8; mb++) o[mb] *= alpha;
      // P^T (regs) -> Ps as (qrow, key), packed b64 writes
      #pragma unroll
      for (int mb = 0; mb < 4; mb++) {
        bf16x4_t pk;
        pk[0] = (bf16_t)sacc[mb][0]; pk[1] = (bf16_t)sacc[mb][1];
        pk[2] = (bf16_t)sacc[mb][2]; pk[3] = (bf16_t)sacc[mb][3];
        *(bf16x4_t*)&Ps[wave][l16*72 + mb*16 + quad*4] = pk;
      }
      // O^T += V^T P  (A=V^T, B=P; wave-local Ps, no barrier)
      bf16x8_t pf[2];
      #pragma unroll
      for (int kc = 0; kc < 2; kc++)
        pf[kc] = *(const bf16x8_t*)&Ps[wave][l16*72 + kc*32 + quad*8];
      #pragma unroll
      for (int mb = 0; mb < 8; mb++)
        #pragma unroll
        for (int kc = 0; kc < 2; kc++) {
          bf16x8_t vf = *(const bf16x8_t*)&Vs[(mb*16 + l16)*72 + kc*32 + quad*8];
          o[mb] = mfma16(vf, pf[kc], o[mb]);
        }
    }
    // epilogue: O^T -> LDS transpose (reuse Ks) -> coalesced b128 global stores
    __syncthreads();  // all waves done reading Ks
    bf16_t* OLw = &Ks[wave * 2176];  // 16 rows x 136
    float invl = 1.0f / lrow;
    #pragma unroll
    for (int mb = 0; mb < 8; mb++) {
      bf16x4_t pk;
      pk[0] = (bf16_t)(o[mb][0] * invl); pk[1] = (bf16_t)(o[mb][1] * invl);
      pk[2] = (bf16_t)(o[mb][2] * invl); pk[3] = (bf16_t)(o[mb][3] * invl);
      *(bf16x4_t*)&OLw[l16*136 + mb*16 + quad*4] = pk;
    }
    int row = lane & 15, part = lane >> 4;
    int tok = qt*64 + wave*16 + row;
    bf16_t* dst = yb + ((size_t)(b*T_ + tok) * NH + h) * HD + part*32;
    #pragma unroll
    for (int jj = 0; jj < 4; jj++)
      *(bf16x8_t*)(dst + jj*8) = *(const bf16x8_t*)&OLw[row*136 + part*32 + jj*8];
  }
}

extern "C" void kernel_launch(void* const* d_in, const int* in_sizes, int n_in,
                              void* d_out, int out_size, void* d_ws, size_t ws_size,
                              hipStream_t stream) {
  const float* x      = (const float*)d_in[0];
  const float* w_attn = (const float*)d_in[1];
  const float* w_proj = (const float*)d_in[2];
  const float* cosb   = (const float*)d_in[3];
  const float* sinb   = (const float*)d_in[4];
  float* out = (float*)d_out;

  bf16_t* xb  = (bf16_t*)d_ws;             // 8388608 bf16
  bf16_t* wab = xb + 8388608;              // 8388608 bf16
  bf16_t* wpb = wab + 8388608;             // 4194304 bf16
  float*  qkv = (float*)(wpb + 4194304);   // 16777216 fp32
  bf16_t* qb  = (bf16_t*)(qkv + 16777216); // 8388608 bf16
  bf16_t* kb  = qb + 8388608;              // 4194304 bf16
  bf16_t* vt  = kb + 4194304;              // 4194304 bf16 (b, kvh, d, t)
  bf16_t* yb  = vt + 4194304;              // 8388608 bf16

  cvt_kernel<<<8192, 256, 0, stream>>>(x, xb, 8388608);
  cvt_kernel<<<8192, 256, 0, stream>>>(w_attn, wab, 8388608);
  cvt_kernel<<<4096, 256, 0, stream>>>(w_proj, wpb, 4194304);

  // qkv = x @ w_attn^T : M=4096, N=4096, K=2048
  gemm_nt<<<dim3(32, 32), 256, 0, stream>>>(xb, wab, qkv, NTOK, QKVD, C_);

  rope_norm_kernel<<<dim3(6, 4096), 256, 0, stream>>>(qkv, cosb, sinb, qb, kb);
  transpose_v<<<dim3(32, 16), 256, 0, stream>>>(qkv, vt);

  attn_kernel<<<dim3(16, 32), 256, 0, stream>>>(qb, kb, vt, yb);

  // out = y @ w_proj^T : M=4096, N=2048, K=2048
  gemm_nt<<<dim3(16, 32), 256, 0, stream>>>(yb, wpb, out, NTOK, C_, C_);
}

// Round 3
// 353.893 us; speedup vs baseline: 1.9471x; 1.0161x over previous
//
#include <hip/hip_runtime.h>

#define B_ 2
#define T_ 2048
#define NH 16
#define NKV 8
#define HD 128
#define C_ 2048
#define KVD (NKV*HD)       // 1024
#define QKVD (C_ + 2*KVD)  // 4096
#define NTOK (B_*T_)       // 4096

typedef __bf16 bf16_t;
typedef __bf16 bf16x4_t __attribute__((ext_vector_type(4)));
typedef __bf16 bf16x8_t __attribute__((ext_vector_type(8)));
typedef float f32x4_t __attribute__((ext_vector_type(4)));
typedef float f32x16_t __attribute__((ext_vector_type(16)));

__device__ __forceinline__ f32x4_t mfma16(bf16x8_t a, bf16x8_t b, f32x4_t c) {
  return __builtin_amdgcn_mfma_f32_16x16x32_bf16(a, b, c, 0, 0, 0);
}
__device__ __forceinline__ f32x16_t mfma32(bf16x8_t a, bf16x8_t b, f32x16_t c) {
  return __builtin_amdgcn_mfma_f32_32x32x16_bf16(a, b, c, 0, 0, 0);
}
__device__ __forceinline__ f32x16_t zero16() {
  f32x16_t z;
  #pragma unroll
  for (int i = 0; i < 16; i++) z[i] = 0.f;
  return z;
}

// async global->LDS, 16B per lane
#define GLDS16(gp, lp) __builtin_amdgcn_global_load_lds( \
    (const __attribute__((address_space(1))) void*)(gp), \
    (__attribute__((address_space(3))) void*)(lp), 16, 0, 0)

// ---------------- fused fp32 -> bf16 convert for x / w_attn / w_proj ----------------
__global__ __launch_bounds__(256) void cvt3_kernel(const float* __restrict__ s0, bf16_t* __restrict__ d0,
                                                   const float* __restrict__ s1, bf16_t* __restrict__ d1,
                                                   const float* __restrict__ s2, bf16_t* __restrict__ d2) {
  int bid = blockIdx.x;
  const float* s; bf16_t* d; int off;
  if (bid < 8192)       { s = s0; d = d0; off = bid; }
  else if (bid < 16384) { s = s1; d = d1; off = bid - 8192; }
  else                  { s = s2; d = d2; off = bid - 16384; }
  int i = (off * 256 + threadIdx.x) * 4;
  const float4 v = *(const float4*)(s + i);
  bf16x4_t o;
  o[0] = (bf16_t)v.x; o[1] = (bf16_t)v.y; o[2] = (bf16_t)v.z; o[3] = (bf16_t)v.w;
  *(bf16x4_t*)(d + i) = o;
}

// ---------------- bf16 NT GEMM (m97 pattern): C = A B^T; out fp32 (Cf) or bf16 (Cb) ----------------
__global__ void gemm_nt(const bf16_t* __restrict__ A, const bf16_t* __restrict__ Bm,
                        float* __restrict__ Cf, bf16_t* __restrict__ Cb, int M, int N, int K) {
  __shared__ bf16_t As[128*32];
  __shared__ bf16_t Bs[128*32];
  int tid = threadIdx.x;
  int wave = tid >> 6, lane = tid & 63;
  int quad = lane >> 4, l16 = lane & 15;
  int wm = (wave >> 1) * 64, wn = (wave & 1) * 64;
  int bm = blockIdx.y * 128, bn = blockIdx.x * 128;
  int grow = wave * 32 + (lane >> 2);
  int gcol = (lane & 3) * 8;
  const bf16_t* pa = A + (size_t)(bm + grow) * K + gcol;
  const bf16_t* pb = Bm + (size_t)(bn + grow) * K + gcol;
  bf16_t* lA0 = &As[(wave * 32) * 32];
  bf16_t* lA1 = &As[(wave * 32 + 16) * 32];
  bf16_t* lB0 = &Bs[(wave * 32) * 32];
  bf16_t* lB1 = &Bs[(wave * 32 + 16) * 32];
  f32x4_t acc[4][4];
  #pragma unroll
  for (int i = 0; i < 4; i++)
    #pragma unroll
    for (int j = 0; j < 4; j++) acc[i][j] = (f32x4_t){0.f,0.f,0.f,0.f};
  for (int k0 = 0; k0 < K; k0 += 32) {
    __syncthreads();
    GLDS16(pa + k0, lA0);
    GLDS16(pa + (size_t)16 * K + k0, lA1);
    GLDS16(pb + k0, lB0);
    GLDS16(pb + (size_t)16 * K + k0, lB1);
    __syncthreads();
    bf16x8_t af[4], bfr[4];
    #pragma unroll
    for (int i = 0; i < 4; i++) {
      af[i]  = *(const bf16x8_t*)&As[(wm + i*16 + l16)*32 + quad*8];
      bfr[i] = *(const bf16x8_t*)&Bs[(wn + i*16 + l16)*32 + quad*8];
    }
    #pragma unroll
    for (int i = 0; i < 4; i++)
      #pragma unroll
      for (int j = 0; j < 4; j++)
        acc[i][j] = mfma16(af[i], bfr[j], acc[i][j]);
  }
  // C/D layout: col = lane&15, row = quad*4 + reg
  if (Cb) {
    #pragma unroll
    for (int i = 0; i < 4; i++)
      #pragma unroll
      for (int j = 0; j < 4; j++) {
        int row0 = bm + wm + i*16 + quad*4;
        int col  = bn + wn + j*16 + l16;
        #pragma unroll
        for (int r = 0; r < 4; r++)
          Cb[(size_t)(row0 + r) * N + col] = (bf16_t)acc[i][j][r];
      }
  } else {
    #pragma unroll
    for (int i = 0; i < 4; i++)
      #pragma unroll
      for (int j = 0; j < 4; j++) {
        int row0 = bm + wm + i*16 + quad*4;
        int col  = bn + wn + j*16 + l16;
        #pragma unroll
        for (int r = 0; r < 4; r++)
          Cf[(size_t)(row0 + r) * N + col] = acc[i][j][r];
      }
  }
}

// ---------------- RoPE + RMSNorm, bf16 qkv -> q/k bf16 ----------------
__global__ __launch_bounds__(256) void rope_norm_kernel(const bf16_t* __restrict__ qkv,
    const float* __restrict__ cosb, const float* __restrict__ sinb,
    bf16_t* __restrict__ qb, bf16_t* __restrict__ kb) {
  int token = blockIdx.y;
  int slot = blockIdx.x * 4 + (threadIdx.x >> 6);
  int lane = threadIdx.x & 63;
  int b = token >> 11, s = token & 2047;
  const bf16_t* row = qkv + (size_t)token * QKVD;
  int base_in = (slot < 16) ? slot * HD : C_ + (slot - 16) * HD;
  float x1 = (float)row[base_in + lane];
  float x2 = (float)row[base_in + 64 + lane];
  float c = cosb[s*64 + lane], sn = sinb[s*64 + lane];
  float y1 = x1*c + x2*sn;
  float y2 = x2*c - x1*sn;
  float ss = y1*y1 + y2*y2;
  ss += __shfl_xor(ss, 1);  ss += __shfl_xor(ss, 2);  ss += __shfl_xor(ss, 4);
  ss += __shfl_xor(ss, 8);  ss += __shfl_xor(ss, 16); ss += __shfl_xor(ss, 32);
  float r = rsqrtf(ss * (1.0f/128.0f) + 1.1920929e-07f);
  bf16_t* dst;
  if (slot < 16) {
    r *= 0.08838834764831845f * 1.4426950408889634f;  // 1/sqrt(128) * log2(e)
    dst = qb + ((size_t)(b*NH + slot) * T_ + s) * HD;
  } else {
    dst = kb + ((size_t)(b*NKV + (slot-16)) * T_ + s) * HD;
  }
  dst[lane]      = (bf16_t)(y1 * r);
  dst[lane + 64] = (bf16_t)(y2 * r);
}

// ---------------- V: transpose bf16 qkv slice to (b, kvh, d, t) ----------------
__global__ __launch_bounds__(256) void transpose_v(const bf16_t* __restrict__ qkv,
                                                   bf16_t* __restrict__ vt) {
  __shared__ bf16_t TT[64*136];   // (tok, d) pad 128->136
  int bk = blockIdx.y;            // b*8 + kv
  int b = bk >> 3, kv = bk & 7;
  int s0 = blockIdx.x * 64;
  int tid = threadIdx.x;
  int row = tid >> 2, c0 = (tid & 3) * 32;
  const bf16_t* src = qkv + (size_t)(b*T_ + s0 + row) * QKVD + C_ + KVD + kv*HD + c0;
  #pragma unroll
  for (int s4 = 0; s4 < 4; s4++)
    *(bf16x8_t*)&TT[row*136 + c0 + s4*8] = *(const bf16x8_t*)(src + s4*8);
  __syncthreads();
  #pragma unroll
  for (int s2 = 0; s2 < 2; s2++) {
    int d = (tid >> 2) + s2*64;
    #pragma unroll
    for (int s = 0; s < 2; s++) {
      int g = (tid & 3) * 8 + s*32;
      bf16x8_t pk;
      #pragma unroll
      for (int e = 0; e < 8; e++) pk[e] = TT[(g + e)*136 + d];
      *(bf16x8_t*)(vt + ((size_t)bk * HD + d) * T_ + s0 + g) = pk;
    }
  }
}

// ---------------- flash attention: 32x32x16 MFMA, 128 q-rows/block ----------------
// S^T = K Q^T: C col = lane&31 = q-row (one per lane), row = key. Softmax: 1 shuffle.
// O^T = V^T P. Each wave: 32 q-rows. 64-key tiles. Balanced grid swizzle: blocks
// L and L+256 share bh with complementary qt (sum 15) -> per-CU 34 tiles exact.
__global__ __launch_bounds__(256, 2) void attn_kernel(const bf16_t* __restrict__ qb,
    const bf16_t* __restrict__ kb, const bf16_t* __restrict__ vt, bf16_t* __restrict__ yb) {
  __shared__ bf16_t Ks[64*136];    // (key, d) pad 128->136      17408 B
  __shared__ bf16_t Vs[128*72];    // (d, key) pad 64->72        18432 B
  __shared__ bf16_t Ps[4][32*72];  // per-wave P (q, key) pad    18432 B  -> 54272 B total (2 blocks/CU)
  int L = blockIdx.x;
  int s = (L >> 8) & 1;
  int bh = (L >> 3) & 31;
  int qt = s ? (15 - 2*(L & 7)) : (2*(L & 7));
  int b = bh >> 4, h = bh & 15, kvh = h >> 1;
  int tid = threadIdx.x, wave = tid >> 6, lane = tid & 63;
  int l32 = lane & 31, half = lane >> 5;
  const bf16_t* Qp = qb + (size_t)bh * T_ * HD;
  const bf16_t* Kp = kb + (size_t)(b*NKV + kvh) * T_ * HD;
  const bf16_t* Vt = vt + (size_t)(b*NKV + kvh) * HD * T_;

  int qrow = qt*128 + wave*32 + l32;   // this lane's q row (both halves same q)
  bf16x8_t qf[8];                      // B-frag: B[k=half*8+j][n=l32], k-chunks over d
  #pragma unroll
  for (int kc = 0; kc < 8; kc++)
    qf[kc] = *(const bf16x8_t*)(Qp + (size_t)qrow * HD + kc*16 + half*8);

  float mrow = -1e30f, lrow = 0.f;
  f32x16_t o[4];                       // O^T: row = d (4 x 32), col = q = l32
  #pragma unroll
  for (int mb = 0; mb < 4; mb++) o[mb] = zero16();

  int krow = tid >> 2, kcb = (tid & 3) * 32;   // K staging: 64 rows x 128
  int vd = tid >> 1,  vcb = (tid & 1) * 32;    // V staging: 128 rows x 64

  int nkt = 2*qt + 2;
  for (int kt = 0; kt < nkt; kt++) {
    int k0 = kt * 64;
    __syncthreads();  // previous tile's frag reads complete
    {
      const bf16_t* src = Kp + (size_t)(k0 + krow) * HD + kcb;
      #pragma unroll
      for (int ss2 = 0; ss2 < 4; ss2++)
        *(bf16x8_t*)&Ks[krow*136 + kcb + ss2*8] = *(const bf16x8_t*)(src + ss2*8);
    }
    {
      const bf16_t* src = Vt + (size_t)vd * T_ + k0 + vcb;
      #pragma unroll
      for (int ss2 = 0; ss2 < 4; ss2++)
        *(bf16x8_t*)&Vs[vd*72 + vcb + ss2*8] = *(const bf16x8_t*)(src + ss2*8);
    }
    __syncthreads();

    // S^T = K Q^T : sacc[mb] rows = keys mb*32 + (r&3)+8*(r>>2)+4*half, col q = l32
    f32x16_t sacc[2];
    sacc[0] = zero16(); sacc[1] = zero16();
    #pragma unroll
    for (int kc = 0; kc < 8; kc++) {
      #pragma unroll
      for (int mb = 0; mb < 2; mb++) {
        bf16x8_t kf = *(const bf16x8_t*)&Ks[(mb*32 + l32)*136 + kc*16 + half*8];
        sacc[mb] = mfma32(kf, qf[kc], sacc[mb]);
      }
    }
    // causal mask (only needed near diagonal)
    if (k0 + 63 > qt*128 + wave*32) {
      #pragma unroll
      for (int mb = 0; mb < 2; mb++)
        #pragma unroll
        for (int r = 0; r < 16; r++) {
          int key = k0 + mb*32 + (r&3) + 8*(r>>2) + 4*half;
          if (key > qrow) sacc[mb][r] = -1e30f;
        }
    }
    // online softmax: lane owns one q-row; reduce over lane^32 only
    float mx = -1e30f;
    #pragma unroll
    for (int mb = 0; mb < 2; mb++)
      #pragma unroll
      for (int r = 0; r < 16; r++) mx = fmaxf(mx, sacc[mb][r]);
    mx = fmaxf(mx, __shfl_xor(mx, 32));
    float mnew = fmaxf(mrow, mx);
    float alpha = exp2f(mrow - mnew);
    mrow = mnew;
    float rs = 0.f;
    #pragma unroll
    for (int mb = 0; mb < 2; mb++)
      #pragma unroll
      for (int r = 0; r < 16; r++) {
        float p = exp2f(sacc[mb][r] - mnew);
        sacc[mb][r] = p;
        rs += p;
      }
    rs += __shfl_xor(rs, 32);
    lrow = lrow * alpha + rs;
    #pragma unroll
    for (int mb = 0; mb < 4; mb++) o[mb] = o[mb] * alpha;
    // P -> Ps as (q, key): regs rr*4+e are keys mb*32 + rr*8 + half*4 + e (consecutive)
    #pragma unroll
    for (int mb = 0; mb < 2; mb++)
      #pragma unroll
      for (int rr = 0; rr < 4; rr++) {
        bf16x4_t pk;
        pk[0] = (bf16_t)sacc[mb][rr*4+0]; pk[1] = (bf16_t)sacc[mb][rr*4+1];
        pk[2] = (bf16_t)sacc[mb][rr*4+2]; pk[3] = (bf16_t)sacc[mb][rr*4+3];
        *(bf16x4_t*)&Ps[wave][l32*72 + mb*32 + rr*8 + half*4] = pk;
      }
    // O^T += V^T P (wave-local Ps; lgkmcnt ordering within wave)
    bf16x8_t pf[4];
    #pragma unroll
    for (int kc = 0; kc < 4; kc++)
      pf[kc] = *(const bf16x8_t*)&Ps[wave][l32*72 + kc*16 + half*8];
    #pragma unroll
    for (int mb = 0; mb < 4; mb++)
      #pragma unroll
      for (int kc = 0; kc < 4; kc++) {
        bf16x8_t vf = *(const bf16x8_t*)&Vs[(mb*32 + l32)*72 + kc*16 + half*8];
        o[mb] = mfma32(vf, pf[kc], o[mb]);
      }
  }
  // epilogue: O^T -> LDS transpose -> coalesced b128 stores
  __syncthreads();  // all waves done with Ks/Vs
  bf16_t* OL = (wave < 2) ? &Ks[wave * 4352] : &Vs[(wave - 2) * 4352];  // 32 x 136
  float invl = 1.0f / lrow;
  #pragma unroll
  for (int mb = 0; mb < 4; mb++)
    #pragma unroll
    for (int rr = 0; rr < 4; rr++) {
      bf16x4_t pk;
      pk[0] = (bf16_t)(o[mb][rr*4+0] * invl); pk[1] = (bf16_t)(o[mb][rr*4+1] * invl);
      pk[2] = (bf16_t)(o[mb][rr*4+2] * invl); pk[3] = (bf16_t)(o[mb][rr*4+3] * invl);
      *(bf16x4_t*)&OL[l32*136 + mb*32 + rr*8 + half*4] = pk;
    }
  int row = l32, seg = half;
  int tok = qt*128 + wave*32 + row;
  bf16_t* dst = yb + ((size_t)(b*T_ + tok) * NH + h) * HD + seg*64;
  #pragma unroll
  for (int j = 0; j < 8; j++)
    *(bf16x8_t*)(dst + j*8) = *(const bf16x8_t*)&OL[row*136 + seg*64 + j*8];
}

extern "C" void kernel_launch(void* const* d_in, const int* in_sizes, int n_in,
                              void* d_out, int out_size, void* d_ws, size_t ws_size,
                              hipStream_t stream) {
  const float* x      = (const float*)d_in[0];
  const float* w_attn = (const float*)d_in[1];
  const float* w_proj = (const float*)d_in[2];
  const float* cosb   = (const float*)d_in[3];
  const float* sinb   = (const float*)d_in[4];
  float* out = (float*)d_out;

  bf16_t* xb   = (bf16_t*)d_ws;           // 8388608
  bf16_t* wab  = xb + 8388608;            // 8388608
  bf16_t* wpb  = wab + 8388608;           // 4194304
  bf16_t* qkvb = wpb + 4194304;           // 16777216
  bf16_t* qb   = qkvb + 16777216;         // 8388608
  bf16_t* kb   = qb + 8388608;            // 4194304
  bf16_t* vt   = kb + 4194304;            // 4194304 (b, kvh, d, t)
  bf16_t* yb   = vt + 4194304;            // 8388608

  cvt3_kernel<<<20480, 256, 0, stream>>>(x, xb, w_attn, wab, w_proj, wpb);

  // qkv = x @ w_attn^T : M=4096, N=4096, K=2048 (bf16 out)
  gemm_nt<<<dim3(32, 32), 256, 0, stream>>>(xb, wab, nullptr, qkvb, NTOK, QKVD, C_);

  rope_norm_kernel<<<dim3(6, 4096), 256, 0, stream>>>(qkvb, cosb, sinb, qb, kb);
  transpose_v<<<dim3(32, 16), 256, 0, stream>>>(qkvb, vt);

  attn_kernel<<<512, 256, 0, stream>>>(qb, kb, vt, yb);

  // out = y @ w_proj^T : M=4096, N=2048, K=2048 (fp32 out)
  gemm_nt<<<dim3(16, 32), 256, 0, stream>>>(yb, wpb, out, nullptr, NTOK, C_, C_);
}